// Round 2
// baseline (1456.402 us; speedup 1.0000x reference)
//
#include <hip/hip_runtime.h>
#include <hip/hip_bf16.h>

// Problem constants
#define C1c 256
#define C2c 256
#define NBAT 16
#define HH 56
#define WW 56
#define KS 13
#define PADc 6
#define HP 68                    // 56 + 2*6
#define NPIX (NBAT*HH*WW)        // 50176
#define PIXTILES 196             // NPIX / 256
#define KSTEPS2 1352             // 169 * 8 steps of BK=32, order (kh, q, kw)

typedef __bf16 bf16;
typedef bf16 bf16x8 __attribute__((ext_vector_type(8)));
typedef float floatx4 __attribute__((ext_vector_type(4)));
typedef float floatx16 __attribute__((ext_vector_type(16)));

// Workspace layout (bf16):
//   xT : [NBAT*HP*HP][C1]          = 18,939,904 elems (37,879,808 B)
//   wT : [1352][256][32]           = 11,075,584 elems (22,151,168 B)
#define XT_ELEMS ((size_t)NBAT*HP*HP*C1c)
#define WT_ELEMS ((size_t)KSTEPS2*256*32)

// ---------------------------------------------------------------------------
// Pre-pass 1: x (N,C,H,W) fp32 -> xT [(n*68+hp)*68+wp][c1] bf16, padded.
// Coalesced: block = (n, hp); waves read contiguous 56-float rows per channel,
// LDS-transpose [iw][c] (row stride 258 bf16 = 129 dwords, odd -> bank-clean),
// then write xT rows as 16B chunks.
// ---------------------------------------------------------------------------
__global__ __launch_bounds__(256) void xform_x(const float* __restrict__ x,
                                               bf16* __restrict__ xT) {
  __shared__ bf16 tile[56][258];
  const int tid = threadIdx.x;
  const int n = blockIdx.x / HP;
  const int hp = blockIdx.x - n * HP;
  const int ih = hp - PADc;
  const size_t pos_base = (size_t)(n * HP + hp) * HP * C1c;

  if (ih < 0 || ih >= HH) {
    // whole 68-row slab is padding: zero-fill 68*256 bf16
#pragma unroll 1
    for (int i = tid; i < HP * 32; i += 256) {
      int wp = i >> 5, g = i & 31;
      *(uint4*)(xT + pos_base + wp * C1c + g * 8) = (uint4){0u, 0u, 0u, 0u};
    }
    return;
  }

  const int wave = tid >> 6, lane = tid & 63;
#pragma unroll 4
  for (int i = 0; i < 64; ++i) {
    int c = i * 4 + wave;                       // covers 0..255 exactly
    if (lane < WW) {
      float v = x[(((size_t)n * C1c + c) * HH + ih) * WW + lane];
      tile[lane][c] = (bf16)v;
    }
  }
  __syncthreads();

#pragma unroll 1
  for (int i = tid; i < HP * 32; i += 256) {
    int wp = i >> 5, g = i & 31;
    int iw = wp - PADc;
    uint4 o;
    if (iw >= 0 && iw < WW) {
      const uint* lp = (const uint*)&tile[iw][g * 8];   // dword-aligned
      o.x = lp[0]; o.y = lp[1]; o.z = lp[2]; o.w = lp[3];
    } else {
      o = (uint4){0u, 0u, 0u, 0u};
    }
    *(uint4*)(xT + pos_base + wp * C1c + g * 8) = o;
  }
}

// ---------------------------------------------------------------------------
// Pre-pass 2: w (C2,C1,13,13) fp32 -> wT [kk][c2][32] bf16
//   kk = (kh*8 + q)*13 + kw,  c1 = q*32 + e   (kw innermost for xT L2 reuse)
// ---------------------------------------------------------------------------
__global__ __launch_bounds__(256) void xform_w(const float* __restrict__ w,
                                               bf16* __restrict__ wT) {
  int j = blockIdx.x * 256 + threadIdx.x;   // KSTEPS2*256*4 threads
  int part = j & 3;
  int c2 = (j >> 2) & 255;
  int kk = j >> 10;            // 0..1351
  int kw = kk % 13;
  int t = kk / 13;
  int q = t & 7;
  int kh = t >> 3;
  int c1 = q * 32 + part * 8;
  const float* wp = w + ((size_t)c2 * C1c + c1) * (KS * KS) + kh * KS + kw;
  bf16x8 v;
#pragma unroll
  for (int i = 0; i < 8; i++) v[i] = (bf16)wp[(size_t)i * KS * KS];
  *(bf16x8*)(wT + (size_t)j * 8) = v;
}

// ---------------------------------------------------------------------------
// Main: implicit-GEMM conv + BN + SiLU.
//   Block tile: 256 c2 x 256 pixels, BK=32, 8 waves (2M x 4N),
//   per-wave 128x64 via mfma_f32_32x32x16_bf16: 4x2 frags x 2 K-halves,
//   12 ds_read_b128 feed 16 MFMA (32K FLOP each) per wave-step.
//   m201-style cadence per step: 2 phases of
//     {6 ds_reads + 2 gloads -> s_barrier -> setprio(1) 8 MFMA setprio(0)
//      -> s_barrier}; counted vmcnt(4) at end of step. ds_read latency
//   overlaps barrier convergence; 3-deep buffer ring (prefetch distance 2).
//   XOR swizzle slot = part ^ ((row>>1)&3), applied on *source* addresses.
//   Grid = 196 blocks, bijective XCD swizzle (q=24, r=4).
// ---------------------------------------------------------------------------
__device__ __forceinline__ void gload_lds16(const bf16* g, bf16* l) {
  __builtin_amdgcn_global_load_lds(
      (const __attribute__((address_space(1))) void*)(g),
      (__attribute__((address_space(3))) void*)(l),
      16, 0, 0);
}

__global__ __launch_bounds__(512, 2) void conv_mfma(
    const bf16* __restrict__ xT, const bf16* __restrict__ wT,
    const float* __restrict__ gamma, const float* __restrict__ beta,
    const float* __restrict__ rmean, const float* __restrict__ rvar,
    float* __restrict__ out) {
  __shared__ __attribute__((aligned(16))) bf16 As[3][256 * 32];
  __shared__ __attribute__((aligned(16))) bf16 Bs[3][256 * 32];
  __shared__ float sS[256];
  __shared__ float sB[256];

  const int tid = threadIdx.x;
  const int lane = tid & 63;
  const int wave = tid >> 6;           // 0..7
  const int wm = wave >> 2, wn = wave & 3;

  // bijective XCD swizzle over 196 workgroups: q=24, r=4
  const int orig = blockIdx.x;
  const int xcd = orig & 7, kb = orig >> 3;
  const int pixt = (xcd < 4 ? xcd * 25 : 100 + (xcd - 4) * 24) + kb;
  const int pixbase = pixt * 256;

  // BN scale/bias for all 256 c2 rows
  if (tid < 256) {
    float s = gamma[tid] * rsqrtf(rvar[tid] + 1e-5f);
    sS[tid] = s;
    sB[tid] = beta[tid] - rmean[tid] * s;
  }
  __syncthreads();

  // --- staging lane constants (XOR-swizzled source granule) ---
  const int part = tid & 3;                  // LDS slot within 64B row
  const int row0 = tid >> 2;                 // 0..127: row within 128-row issue
  const int srcg = (part ^ ((row0 >> 1) & 3)) * 8;  // source granule elems

  // A: issue l covers c2 rows [l*128, l*128+128)
  const int aOff0 = row0 * 32 + srcg;
  const int aOff1 = aOff0 + 128 * 32;

  // B: issue l covers pixels [pixbase + l*128, +128)
  int pOff0, pOff1;
  {
    int pix = pixbase + row0;
    int n = pix / (HH * WW);
    int rr = pix - n * (HH * WW);
    int oh = rr / WW;
    int ow = rr - oh * WW;
    pOff0 = ((n * HP + oh) * HP + ow) * C1c + srcg;
    pix += 128;
    n = pix / (HH * WW);
    rr = pix - n * (HH * WW);
    oh = rr / WW;
    ow = rr - oh * WW;
    pOff1 = ((n * HP + oh) * HP + ow) * C1c + srcg;
  }

  // per-wave LDS destination base, in elems (gload dest = base + lane*16B)
  const int ldsA0 = wave * 512;

  // fragment-read lane constants (same XOR swizzle; constant per lane)
  const int mrow = lane & 31;                      // 32x32 frag row
  const int kg = lane >> 5;                        // source k granule (0..1)
  const int sw = (mrow >> 1) & 3;
  const int g0 = ((kg)     ^ sw) * 8;              // kh=0 swizzled LDS offset
  const int g1 = ((kg + 2) ^ sw) * 8;              // kh=1
  const int aRB = (wm * 128 + mrow) * 32;          // + m*1024
  const int bRB = (wn * 64 + mrow) * 32;           // + n*1024

  floatx16 acc[4][2];
#pragma unroll
  for (int mi = 0; mi < 4; mi++)
#pragma unroll
    for (int ni = 0; ni < 2; ni++)
#pragma unroll
      for (int r = 0; r < 16; r++) acc[mi][ni][r] = 0.f;

  // prologue: stage step 0 -> buf0, step 1 -> buf1  (order A,A,B,B per step)
  gload_lds16(wT + aOff0, &As[0][ldsA0]);
  gload_lds16(wT + aOff1, &As[0][4096 + ldsA0]);
  gload_lds16(xT + pOff0, &Bs[0][ldsA0]);
  gload_lds16(xT + pOff1, &Bs[0][4096 + ldsA0]);
  gload_lds16(wT + 8192 + aOff0, &As[1][ldsA0]);
  gload_lds16(wT + 8192 + aOff1, &As[1][4096 + ldsA0]);
  gload_lds16(xT + pOff0 + C1c, &Bs[1][ldsA0]);    // step1: kw=1
  gload_lds16(xT + pOff1 + C1c, &Bs[1][4096 + ldsA0]);
  asm volatile("s_waitcnt vmcnt(4)" ::: "memory");  // step-0 loads landed
  __builtin_amdgcn_s_barrier();

  // rolling prefetch state for step kn = kk + 2
  int kwn = 2, qn = 0, khn = 0;
  const bf16* aPre = wT + 2 * 8192;

  auto do_step = [&](const bf16* Ac, const bf16* Bc, bf16* An, bf16* Bn) {
    // entering: this step's buffer landed & visible (vmcnt+barrier done)

    // ---- phase 0 (kh=0): reads issued BEFORE barrier (latency overlap) ----
    bf16x8 a0[4], b0[2];
#pragma unroll
    for (int mi = 0; mi < 4; mi++)
      a0[mi] = *(const bf16x8*)(Ac + aRB + mi * 1024 + g0);
#pragma unroll
    for (int ni = 0; ni < 2; ni++)
      b0[ni] = *(const bf16x8*)(Bc + bRB + ni * 1024 + g0);
    gload_lds16(aPre + aOff0, An + ldsA0);
    gload_lds16(aPre + aOff1, An + 4096 + ldsA0);
    __builtin_amdgcn_sched_barrier(0);
    __builtin_amdgcn_s_barrier();
    __builtin_amdgcn_s_setprio(1);
#pragma unroll
    for (int mi = 0; mi < 4; mi++)
#pragma unroll
      for (int ni = 0; ni < 2; ni++)
        acc[mi][ni] = __builtin_amdgcn_mfma_f32_32x32x16_bf16(
            a0[mi], b0[ni], acc[mi][ni], 0, 0, 0);
    __builtin_amdgcn_s_setprio(0);
    __builtin_amdgcn_s_barrier();

    // ---- phase 1 (kh=1) ----
    bf16x8 a1[4], b1[2];
#pragma unroll
    for (int mi = 0; mi < 4; mi++)
      a1[mi] = *(const bf16x8*)(Ac + aRB + mi * 1024 + g1);
#pragma unroll
    for (int ni = 0; ni < 2; ni++)
      b1[ni] = *(const bf16x8*)(Bc + bRB + ni * 1024 + g1);
    int bOn = (khn * HP + kwn) * C1c + qn * 32;
    gload_lds16(xT + pOff0 + bOn, Bn + ldsA0);
    gload_lds16(xT + pOff1 + bOn, Bn + 4096 + ldsA0);
    // advance prefetch counters (kw innermost)
    kwn++; aPre += 8192;
    if (kwn == 13) {
      kwn = 0; qn++;
      if (qn == 8) {
        qn = 0; khn++;
        if (khn == 13) { khn = 0; aPre = wT; }  // tail dummies wrap to step 0
      }
    }
    __builtin_amdgcn_sched_barrier(0);
    __builtin_amdgcn_s_barrier();
    __builtin_amdgcn_s_setprio(1);
#pragma unroll
    for (int mi = 0; mi < 4; mi++)
#pragma unroll
      for (int ni = 0; ni < 2; ni++)
        acc[mi][ni] = __builtin_amdgcn_mfma_f32_32x32x16_bf16(
            a1[mi], b1[ni], acc[mi][ni], 0, 0, 0);
    __builtin_amdgcn_s_setprio(0);
    asm volatile("s_waitcnt vmcnt(4)" ::: "memory");  // next step's loads landed
    __builtin_amdgcn_s_barrier();
  };

#pragma unroll 1
  for (int kk = 0; kk < KSTEPS2 - 2; kk += 3) {
    do_step(As[0], Bs[0], As[2], Bs[2]);
    do_step(As[1], Bs[1], As[0], Bs[0]);
    do_step(As[2], Bs[2], As[1], Bs[1]);
  }
  // tail: steps 1350 (buf0), 1351 (buf1); prefetches are harmless dummies
  do_step(As[0], Bs[0], As[2], Bs[2]);
  do_step(As[1], Bs[1], As[0], Bs[0]);

  // --- epilogue: BN + SiLU, fp32 NCHW stores ---
  // C/D layout (32x32): col = lane&31, row = (reg&3) + 8*(reg>>2) + 4*(lane>>5)
  const int colp = lane & 31;
  const int hi = lane >> 5;
#pragma unroll
  for (int ni = 0; ni < 2; ni++) {
    int pix = pixbase + wn * 64 + ni * 32 + colp;
    int n = pix / (HH * WW);
    int rr = pix - n * (HH * WW);
    size_t obase = (size_t)n * C2c * (HH * WW) + rr;
#pragma unroll
    for (int mi = 0; mi < 4; mi++) {
#pragma unroll
      for (int reg = 0; reg < 16; reg++) {
        int rowl = wm * 128 + mi * 32 + (reg & 3) + 8 * (reg >> 2) + 4 * hi;
        float v = acc[mi][ni][reg];
        v = v * sS[rowl] + sB[rowl];
        float o = v / (1.f + __expf(-v));
        out[obase + (size_t)rowl * (HH * WW)] = o;
      }
    }
  }
}

// ---------------------------------------------------------------------------
extern "C" void kernel_launch(void* const* d_in, const int* in_sizes, int n_in,
                              void* d_out, int out_size, void* d_ws, size_t ws_size,
                              hipStream_t stream) {
  const float* x     = (const float*)d_in[0];
  const float* w     = (const float*)d_in[1];
  const float* gamma = (const float*)d_in[2];
  const float* beta  = (const float*)d_in[3];
  const float* rmean = (const float*)d_in[4];
  const float* rvar  = (const float*)d_in[5];
  float* out = (float*)d_out;

  bf16* xT = (bf16*)d_ws;
  bf16* wT = xT + XT_ELEMS;

  if (ws_size < (XT_ELEMS + WT_ELEMS) * sizeof(bf16)) return;  // need ~57.3 MiB

  xform_x<<<NBAT * HP, 256, 0, stream>>>(x, xT);
  xform_w<<<(KSTEPS2 * 256 * 4) / 256, 256, 0, stream>>>(w, wT);
  conv_mfma<<<PIXTILES, 512, 0, stream>>>(xT, wT, gamma, beta, rmean, rvar, out);
}

// Round 3
// 1198.707 us; speedup vs baseline: 1.2150x; 1.2150x over previous
//
#include <hip/hip_runtime.h>
#include <hip/hip_bf16.h>

// Problem constants
#define C1c 256
#define C2c 256
#define NBAT 16
#define HH 56
#define WW 56
#define KS 13
#define PADc 6
#define HP 68                    // 56 + 2*6
#define NPIX (NBAT*HH*WW)        // 50176
#define PIXTILES 196             // NPIX / 256
#define KSTEPS2 1352             // 169 * 8 steps of BK=32, order (kh, q, kw)

typedef __bf16 bf16;
typedef bf16 bf16x8 __attribute__((ext_vector_type(8)));
typedef float floatx4 __attribute__((ext_vector_type(4)));

// Workspace layout (bf16):
//   xT : [NBAT*HP*HP][C1]          = 18,939,904 elems (37,879,808 B)
//   wT : [1352][256][32]           = 11,075,584 elems (22,151,168 B)
#define XT_ELEMS ((size_t)NBAT*HP*HP*C1c)
#define WT_ELEMS ((size_t)KSTEPS2*256*32)

// ---------------------------------------------------------------------------
// Pre-pass 1: x (N,C,H,W) fp32 -> xT [(n*68+hp)*68+wp][c1] bf16, padded.
// ---------------------------------------------------------------------------
__global__ __launch_bounds__(256) void xform_x(const float* __restrict__ x,
                                               bf16* __restrict__ xT) {
  __shared__ bf16 tile[56][258];
  const int tid = threadIdx.x;
  const int n = blockIdx.x / HP;
  const int hp = blockIdx.x - n * HP;
  const int ih = hp - PADc;
  const size_t pos_base = (size_t)(n * HP + hp) * HP * C1c;

  if (ih < 0 || ih >= HH) {
#pragma unroll 1
    for (int i = tid; i < HP * 32; i += 256) {
      int wp = i >> 5, g = i & 31;
      *(uint4*)(xT + pos_base + wp * C1c + g * 8) = (uint4){0u, 0u, 0u, 0u};
    }
    return;
  }

  const int wave = tid >> 6, lane = tid & 63;
#pragma unroll 4
  for (int i = 0; i < 64; ++i) {
    int c = i * 4 + wave;                       // covers 0..255 exactly
    if (lane < WW) {
      float v = x[(((size_t)n * C1c + c) * HH + ih) * WW + lane];
      tile[lane][c] = (bf16)v;
    }
  }
  __syncthreads();

#pragma unroll 1
  for (int i = tid; i < HP * 32; i += 256) {
    int wp = i >> 5, g = i & 31;
    int iw = wp - PADc;
    uint4 o;
    if (iw >= 0 && iw < WW) {
      const uint* lp = (const uint*)&tile[iw][g * 8];   // dword-aligned
      o.x = lp[0]; o.y = lp[1]; o.z = lp[2]; o.w = lp[3];
    } else {
      o = (uint4){0u, 0u, 0u, 0u};
    }
    *(uint4*)(xT + pos_base + wp * C1c + g * 8) = o;
  }
}

// ---------------------------------------------------------------------------
// Pre-pass 2: w (C2,C1,13,13) fp32 -> wT [kk][c2][32] bf16
//   kk = (kh*8 + q)*13 + kw,  c1 = q*32 + e   (kw innermost for xT L2 reuse)
// ---------------------------------------------------------------------------
__global__ __launch_bounds__(256) void xform_w(const float* __restrict__ w,
                                               bf16* __restrict__ wT) {
  int j = blockIdx.x * 256 + threadIdx.x;   // KSTEPS2*256*4 threads
  int part = j & 3;
  int c2 = (j >> 2) & 255;
  int kk = j >> 10;            // 0..1351
  int kw = kk % 13;
  int t = kk / 13;
  int q = t & 7;
  int kh = t >> 3;
  int c1 = q * 32 + part * 8;
  const float* wp = w + ((size_t)c2 * C1c + c1) * (KS * KS) + kh * KS + kw;
  bf16x8 v;
#pragma unroll
  for (int i = 0; i < 8; i++) v[i] = (bf16)wp[(size_t)i * KS * KS];
  *(bf16x8*)(wT + (size_t)j * 8) = v;
}

// ---------------------------------------------------------------------------
// Main: implicit-GEMM conv + BN + SiLU.
//   Block tile: 256 c2 x 256 pixels, BK=32, 8 waves (2M x 4N),
//   per-wave 128x64 via mfma_f32_16x16x32_bf16, 8x4 frags (R1 addressing —
//   empirically 0 bank conflicts; R2's 32x32 variant measured 1.0e8).
//   Cadence per step (3-buffer ring, prefetch distance 2):
//     phase0: read A0-3+B0-3 frags, issue A-gloads(k+2), sched_barrier,
//             setprio(1) 16 MFMA setprio(0)
//     phase1: read A4-7 frags, issue B-gloads(k+2), sched_barrier,
//             setprio(1) 16 MFMA setprio(0)
//     vmcnt(4) + s_barrier   (ONE barrier/step; mid barriers unnecessary
//                             with the 3-ring — setprio staggers the 2
//                             waves/SIMD so reads hide under MFMA)
//   XOR swizzle slot = part ^ ((row>>1)&3), applied on *source* addresses.
//   Grid = 196 blocks, bijective XCD swizzle (q=24, r=4).
// ---------------------------------------------------------------------------
__device__ __forceinline__ void gload_lds16(const bf16* g, bf16* l) {
  __builtin_amdgcn_global_load_lds(
      (const __attribute__((address_space(1))) void*)(g),
      (__attribute__((address_space(3))) void*)(l),
      16, 0, 0);
}

__global__ __launch_bounds__(512, 2) void conv_mfma(
    const bf16* __restrict__ xT, const bf16* __restrict__ wT,
    const float* __restrict__ gamma, const float* __restrict__ beta,
    const float* __restrict__ rmean, const float* __restrict__ rvar,
    float* __restrict__ out) {
  __shared__ __attribute__((aligned(16))) bf16 As[3][256 * 32];
  __shared__ __attribute__((aligned(16))) bf16 Bs[3][256 * 32];
  __shared__ float sS[256];
  __shared__ float sB[256];

  const int tid = threadIdx.x;
  const int lane = tid & 63;
  const int wave = tid >> 6;           // 0..7
  const int wm = wave >> 2, wn = wave & 3;

  // bijective XCD swizzle over 196 workgroups: q=24, r=4
  const int orig = blockIdx.x;
  const int xcd = orig & 7, kb = orig >> 3;
  const int pixt = (xcd < 4 ? xcd * 25 : 100 + (xcd - 4) * 24) + kb;
  const int pixbase = pixt * 256;

  // BN scale/bias for all 256 c2 rows
  if (tid < 256) {
    float s = gamma[tid] * rsqrtf(rvar[tid] + 1e-5f);
    sS[tid] = s;
    sB[tid] = beta[tid] - rmean[tid] * s;
  }
  __syncthreads();

  // --- staging lane constants (XOR-swizzled source granule) ---
  const int part = tid & 3;                  // LDS slot within 64B row
  const int row0 = tid >> 2;                 // 0..127: row within 128-row issue
  const int srcg = (part ^ ((row0 >> 1) & 3)) * 8;  // source granule elems

  // A: issue l covers c2 rows [l*128, l*128+128)
  const int aOff0 = row0 * 32 + srcg;
  const int aOff1 = aOff0 + 128 * 32;

  // B: issue l covers pixels [pixbase + l*128, +128)
  int pOff0, pOff1;
  {
    int pix = pixbase + row0;
    int n = pix / (HH * WW);
    int rr = pix - n * (HH * WW);
    int oh = rr / WW;
    int ow = rr - oh * WW;
    pOff0 = ((n * HP + oh) * HP + ow) * C1c + srcg;
    pix += 128;
    n = pix / (HH * WW);
    rr = pix - n * (HH * WW);
    oh = rr / WW;
    ow = rr - oh * WW;
    pOff1 = ((n * HP + oh) * HP + ow) * C1c + srcg;
  }

  // per-wave LDS destination base, in elems (gload dest = base + lane*16B)
  const int ldsA0 = wave * 512;

  // fragment-read lane constants (R1 addressing — proven conflict-free)
  const int mrow = lane & 15;
  const int kq = lane >> 4;                        // source k granule (0..3)
  const int g0 = (kq ^ ((mrow >> 1) & 3)) * 8;     // swizzled LDS offset
  const int aRB = (wm * 128 + mrow) * 32 + g0;     // + mi*512
  const int bRB = (wn * 64 + mrow) * 32 + g0;      // + ni*512

  floatx4 acc[8][4];
#pragma unroll
  for (int mi = 0; mi < 8; mi++)
#pragma unroll
    for (int ni = 0; ni < 4; ni++) acc[mi][ni] = (floatx4){0.f, 0.f, 0.f, 0.f};

  // prologue: stage step 0 -> buf0, step 1 -> buf1  (order A,A,B,B per step)
  gload_lds16(wT + aOff0, &As[0][ldsA0]);
  gload_lds16(wT + aOff1, &As[0][4096 + ldsA0]);
  gload_lds16(xT + pOff0, &Bs[0][ldsA0]);
  gload_lds16(xT + pOff1, &Bs[0][4096 + ldsA0]);
  gload_lds16(wT + 8192 + aOff0, &As[1][ldsA0]);
  gload_lds16(wT + 8192 + aOff1, &As[1][4096 + ldsA0]);
  gload_lds16(xT + pOff0 + C1c, &Bs[1][ldsA0]);    // step1: kw=1
  gload_lds16(xT + pOff1 + C1c, &Bs[1][4096 + ldsA0]);
  asm volatile("s_waitcnt vmcnt(4)" ::: "memory");  // step-0 loads landed
  __builtin_amdgcn_s_barrier();

  // rolling prefetch state for step kn = kk + 2
  int kwn = 2, qn = 0, khn = 0;
  const bf16* aPre = wT + 2 * 8192;

  auto do_step = [&](const bf16* Ac, const bf16* Bc, bf16* An, bf16* Bn) {
    // entering: this step's buffer landed & visible to all waves

    bf16x8 af[8], bfr[4];
    // ---- phase 0: frags A0-3 + all B, stage A of step k+2 ----
#pragma unroll
    for (int mi = 0; mi < 4; mi++)
      af[mi] = *(const bf16x8*)(Ac + aRB + mi * 512);
#pragma unroll
    for (int ni = 0; ni < 4; ni++)
      bfr[ni] = *(const bf16x8*)(Bc + bRB + ni * 512);
    gload_lds16(aPre + aOff0, An + ldsA0);
    gload_lds16(aPre + aOff1, An + 4096 + ldsA0);
    __builtin_amdgcn_sched_barrier(0);
    __builtin_amdgcn_s_setprio(1);
#pragma unroll
    for (int mi = 0; mi < 4; mi++)
#pragma unroll
      for (int ni = 0; ni < 4; ni++)
        acc[mi][ni] = __builtin_amdgcn_mfma_f32_16x16x32_bf16(
            af[mi], bfr[ni], acc[mi][ni], 0, 0, 0);
    __builtin_amdgcn_s_setprio(0);
    __builtin_amdgcn_sched_barrier(0);

    // ---- phase 1: frags A4-7, stage B of step k+2 ----
#pragma unroll
    for (int mi = 4; mi < 8; mi++)
      af[mi] = *(const bf16x8*)(Ac + aRB + mi * 512);
    int bOn = (khn * HP + kwn) * C1c + qn * 32;
    gload_lds16(xT + pOff0 + bOn, Bn + ldsA0);
    gload_lds16(xT + pOff1 + bOn, Bn + 4096 + ldsA0);
    // advance prefetch counters (kw innermost)
    kwn++; aPre += 8192;
    if (kwn == 13) {
      kwn = 0; qn++;
      if (qn == 8) {
        qn = 0; khn++;
        if (khn == 13) { khn = 0; aPre = wT; }  // tail dummies wrap to step 0
      }
    }
    __builtin_amdgcn_sched_barrier(0);
    __builtin_amdgcn_s_setprio(1);
#pragma unroll
    for (int mi = 4; mi < 8; mi++)
#pragma unroll
      for (int ni = 0; ni < 4; ni++)
        acc[mi][ni] = __builtin_amdgcn_mfma_f32_16x16x32_bf16(
            af[mi], bfr[ni], acc[mi][ni], 0, 0, 0);
    __builtin_amdgcn_s_setprio(0);

    asm volatile("s_waitcnt vmcnt(4)" ::: "memory");  // next step's loads landed
    __builtin_amdgcn_s_barrier();                     // ONE barrier per step
  };

#pragma unroll 1
  for (int kk = 0; kk < KSTEPS2 - 2; kk += 3) {
    do_step(As[0], Bs[0], As[2], Bs[2]);
    do_step(As[1], Bs[1], As[0], Bs[0]);
    do_step(As[2], Bs[2], As[1], Bs[1]);
  }
  // tail: steps 1350 (buf0), 1351 (buf1); prefetches are harmless dummies
  do_step(As[0], Bs[0], As[2], Bs[2]);
  do_step(As[1], Bs[1], As[0], Bs[0]);

  // --- epilogue: BN + SiLU, fp32 NCHW stores ---
  // C/D layout (16x16): col = lane&15, row = (lane>>4)*4 + reg
  const int colL = lane & 15;
  const int quad = lane >> 4;
#pragma unroll
  for (int ni = 0; ni < 4; ni++) {
    int pix = pixbase + wn * 64 + ni * 16 + colL;
    int n = pix / (HH * WW);
    int rr = pix - n * (HH * WW);
    int oh = rr / WW;
    int ow = rr - oh * WW;
    size_t obase = (size_t)n * C2c * (HH * WW) + (size_t)oh * WW + ow;
#pragma unroll
    for (int mi = 0; mi < 8; mi++) {
      int rowb = wm * 128 + mi * 16 + quad * 4;
#pragma unroll
      for (int r = 0; r < 4; r++) {
        int rowl = rowb + r;
        float v = acc[mi][ni][r];
        v = v * sS[rowl] + sB[rowl];
        float o = v / (1.f + __expf(-v));
        out[obase + (size_t)rowl * (HH * WW)] = o;
      }
    }
  }
}

// ---------------------------------------------------------------------------
extern "C" void kernel_launch(void* const* d_in, const int* in_sizes, int n_in,
                              void* d_out, int out_size, void* d_ws, size_t ws_size,
                              hipStream_t stream) {
  const float* x     = (const float*)d_in[0];
  const float* w     = (const float*)d_in[1];
  const float* gamma = (const float*)d_in[2];
  const float* beta  = (const float*)d_in[3];
  const float* rmean = (const float*)d_in[4];
  const float* rvar  = (const float*)d_in[5];
  float* out = (float*)d_out;

  bf16* xT = (bf16*)d_ws;
  bf16* wT = xT + XT_ELEMS;

  if (ws_size < (XT_ELEMS + WT_ELEMS) * sizeof(bf16)) return;  // need ~57.3 MiB

  xform_x<<<NBAT * HP, 256, 0, stream>>>(x, xT);
  xform_w<<<(KSTEPS2 * 256 * 4) / 256, 256, 0, stream>>>(w, wT);
  conv_mfma<<<PIXTILES, 512, 0, stream>>>(xT, wT, gamma, beta, rmean, rvar, out);
}